// Round 5
// baseline (28.096 us; speedup 1.0000x reference)
//
#include <hip/hip_runtime.h>
#include <hip/hip_bf16.h>

#define BLOCK 256
#define GRID  2048   // 8 blocks/CU x 256 CUs

// BCE-with-logits, masked row sum, via product-of-factors:
//   loss = max(x,0) + log(1+exp(-|x|)) - x*t
// The log terms are accumulated as prod *= (1+e)… (one __logf per THREAD at
// the end instead of one v_log per element). 32 elems/thread, factors in
// (1,2] -> prod <= 2^32, safe in f32; log abs-error ~2e-6.
__device__ __forceinline__ void bce4(const float4 xv, const float4 tv,
                                     float& sum_lin, float& prod) {
    const bool b0 = (tv.x + tv.y) > 0.0f;   // row mask (2 cols/row)
    const bool b1 = (tv.z + tv.w) > 0.0f;
    const float m0 = b0 ? 1.0f : 0.0f;
    const float m1 = b1 ? 1.0f : 0.0f;

    const float f0 = 1.0f + __expf(-fabsf(xv.x));
    const float f1 = 1.0f + __expf(-fabsf(xv.y));
    const float f2 = 1.0f + __expf(-fabsf(xv.z));
    const float f3 = 1.0f + __expf(-fabsf(xv.w));
    prod *= b0 ? (f0 * f1) : 1.0f;          // one cndmask per row
    prod *= b1 ? (f2 * f3) : 1.0f;

    const float r0 = __builtin_fmaf(-xv.x, tv.x, fmaxf(xv.x, 0.0f));
    const float r1 = __builtin_fmaf(-xv.y, tv.y, fmaxf(xv.y, 0.0f));
    const float r2 = __builtin_fmaf(-xv.z, tv.z, fmaxf(xv.z, 0.0f));
    const float r3 = __builtin_fmaf(-xv.w, tv.w, fmaxf(xv.w, 0.0f));
    sum_lin = __builtin_fmaf(m0, r0 + r1, sum_lin);
    sum_lin = __builtin_fmaf(m1, r2 + r3, sum_lin);
}

__global__ __launch_bounds__(BLOCK) void bce_partial_kernel(
        const float4* __restrict__ x4,
        const float4* __restrict__ t4,
        float* __restrict__ partials,   // [GRID] per-block sums, NO atomics
        int n4) {
    float sum_lin = 0.0f;
    float prod    = 1.0f;
    const int stride = gridDim.x * blockDim.x;
    for (int i = blockIdx.x * blockDim.x + threadIdx.x; i < n4; i += 2 * stride) {
        // two independent float4-pairs per iteration (more MLP)
        const float4 xa = x4[i];
        const float4 ta = t4[i];
        bce4(xa, ta, sum_lin, prod);
        const int j = i + stride;
        if (j < n4) {
            const float4 xb = x4[j];
            const float4 tb = t4[j];
            bce4(xb, tb, sum_lin, prod);
        }
    }
    float sum = sum_lin + __logf(prod);  // one log per thread

    // 64-lane wave reduction
    #pragma unroll
    for (int off = 32; off > 0; off >>= 1)
        sum += __shfl_down(sum, off, 64);

    __shared__ float wsum[BLOCK / 64];
    const int lane = threadIdx.x & 63;
    const int wid  = threadIdx.x >> 6;
    if (lane == 0) wsum[wid] = sum;
    __syncthreads();

    if (threadIdx.x == 0) {
        float b = 0.0f;
        #pragma unroll
        for (int w = 0; w < BLOCK / 64; ++w) b += wsum[w];
        partials[blockIdx.x] = b;       // plain store, one per block
    }
}

__global__ __launch_bounds__(BLOCK) void bce_finalize_kernel(
        const float* __restrict__ partials,
        float* __restrict__ out,
        double inv_n) {
    double s = 0.0;
    #pragma unroll
    for (int k = 0; k < GRID / BLOCK; ++k)
        s += (double)partials[threadIdx.x + k * BLOCK];

    #pragma unroll
    for (int off = 32; off > 0; off >>= 1)
        s += __shfl_down(s, off, 64);

    __shared__ double wsum[BLOCK / 64];
    const int lane = threadIdx.x & 63;
    const int wid  = threadIdx.x >> 6;
    if (lane == 0) wsum[wid] = s;
    __syncthreads();

    if (threadIdx.x == 0) {
        double b = 0.0;
        #pragma unroll
        for (int w = 0; w < BLOCK / 64; ++w) b += wsum[w];
        out[0] = (float)(b * inv_n);
    }
}

extern "C" void kernel_launch(void* const* d_in, const int* in_sizes, int n_in,
                              void* d_out, int out_size, void* d_ws, size_t ws_size,
                              hipStream_t stream) {
    const float* x = (const float*)d_in[0];   // inputs  [B,2] f32
    const float* t = (const float*)d_in[1];   // targets [B,2] f32
    float* out = (float*)d_out;
    float* partials = (float*)d_ws;           // 8 KB scratch

    const int n  = in_sizes[0];   // B*C = 16777216
    const int n4 = n / 4;

    bce_partial_kernel<<<GRID, BLOCK, 0, stream>>>(
        (const float4*)x, (const float4*)t, partials, n4);

    bce_finalize_kernel<<<1, BLOCK, 0, stream>>>(partials, out, 1.0 / (double)n);
}